// Round 1
// baseline (335.490 us; speedup 1.0000x reference)
//
#include <hip/hip_runtime.h>
#include <hip/hip_bf16.h>

#define LSEQ 2048
#define NH 16
#define HS 64
#define DIM 1024

typedef __attribute__((ext_vector_type(8))) short short8;
typedef __attribute__((ext_vector_type(4))) float f32x4;

typedef const __attribute__((address_space(1))) void g_void_t;
typedef __attribute__((address_space(3))) void s_void_t;

static __device__ __forceinline__ short f2bf(float f) {
  __hip_bfloat16 h = __float2bfloat16(f);
  return __builtin_bit_cast(short, h);
}
static __device__ __forceinline__ float bf2f(short s) {
  __hip_bfloat16 h = __builtin_bit_cast(__hip_bfloat16, s);
  return __bfloat162float(h);
}

// ---------------- prep kernels ----------------

__global__ void cast_kernel(const float* __restrict__ in, short* __restrict__ out, int n4) {
  int i = blockIdx.x * blockDim.x + threadIdx.x;
  if (i < n4) {
    float4 v = reinterpret_cast<const float4*>(in)[i];
    short4 o;
    o.x = f2bf(v.x); o.y = f2bf(v.y); o.z = f2bf(v.z); o.w = f2bf(v.w);
    reinterpret_cast<short4*>(out)[i] = o;
  }
}

// W: [K][N] f32  ->  Wt: [N][K] bf16
__global__ void transpose_cast_kernel(const float* __restrict__ W, short* __restrict__ Wt,
                                      int K, int N) {
  __shared__ float tile[64][65];
  int k0 = blockIdx.y * 64, n0 = blockIdx.x * 64;
  int t = threadIdx.x;
  int r4 = t >> 6, cc = t & 63;
  for (int i = 0; i < 16; ++i) {
    int row = i * 4 + r4;
    tile[row][cc] = W[(size_t)(k0 + row) * N + (n0 + cc)];
  }
  __syncthreads();
  for (int i = 0; i < 16; ++i) {
    int row = i * 4 + r4;
    Wt[(size_t)(n0 + row) * K + (k0 + cc)] = f2bf(tile[cc][row]);
  }
}

// ---------------- GEMM (A[M][K] bf16 row-major, Bt[N][K] bf16 row-major) ----------------
// MODE 0: epilogue scatters qkv into q/k/v [b,h,l,hs] bf16.  MODE 1: f32 out + bias.

template<int MODE>
__global__ __launch_bounds__(256, 2) void gemm_bt_kernel(
    const short* __restrict__ A, const short* __restrict__ Bt,
    const float* __restrict__ bias, int M, int N, int K,
    short* __restrict__ oq, short* __restrict__ ok, short* __restrict__ ov,
    float* __restrict__ of)
{
  __shared__ short Al[128 * 32];
  __shared__ short Bl[128 * 32];
  const int m0 = blockIdx.y * 128, n0 = blockIdx.x * 128;
  const int t = threadIdx.x;
  const int lane = t & 63, wave = t >> 6;
  const int wr = wave >> 1, wc = wave & 1;
  const int g = lane >> 4, c = lane & 15;
  f32x4 acc[4][4] = {};

  for (int k0 = 0; k0 < K; k0 += 32) {
    __syncthreads();
    for (int i = 0; i < 2; ++i) {
      int ch = i * 256 + t;
      int row = ch >> 2, c8 = ch & 3;
      __builtin_amdgcn_global_load_lds(
          (g_void_t*)(A + (size_t)(m0 + row) * K + k0 + c8 * 8),
          (s_void_t*)(Al + (i * 256 + wave * 64) * 8), 16, 0, 0);
      __builtin_amdgcn_global_load_lds(
          (g_void_t*)(Bt + (size_t)(n0 + row) * K + k0 + c8 * 8),
          (s_void_t*)(Bl + (i * 256 + wave * 64) * 8), 16, 0, 0);
    }
    __syncthreads();
    short8 af[4], bf[4];
#pragma unroll
    for (int mi = 0; mi < 4; ++mi) {
      int row = wr * 64 + mi * 16 + c;
      af[mi] = *reinterpret_cast<const short8*>(Al + row * 32 + g * 8);
    }
#pragma unroll
    for (int ni = 0; ni < 4; ++ni) {
      int row = wc * 64 + ni * 16 + c;
      bf[ni] = *reinterpret_cast<const short8*>(Bl + row * 32 + g * 8);
    }
#pragma unroll
    for (int mi = 0; mi < 4; ++mi)
#pragma unroll
      for (int ni = 0; ni < 4; ++ni)
        acc[mi][ni] = __builtin_amdgcn_mfma_f32_16x16x32_bf16(af[mi], bf[ni], acc[mi][ni], 0, 0, 0);
  }

#pragma unroll
  for (int mi = 0; mi < 4; ++mi)
#pragma unroll
    for (int ni = 0; ni < 4; ++ni) {
      int n = n0 + wc * 64 + ni * 16 + c;
      float bv = bias[n];
#pragma unroll
      for (int r = 0; r < 4; ++r) {
        int m = m0 + wr * 64 + mi * 16 + g * 4 + r;
        float val = acc[mi][ni][r] + bv;
        if (MODE == 0) {
          int which = n >> 10;
          int hh2 = (n >> 6) & 15;
          int d = n & 63;
          int b = m >> 11, ll = m & 2047;
          short* dst = which == 0 ? oq : (which == 1 ? ok : ov);
          dst[(((size_t)b * NH + hh2) * LSEQ + ll) * HS + d] = f2bf(val);
        } else {
          of[(size_t)m * N + n] = val;
        }
      }
    }
}

// ---------------- fused flash attention with relative-position band ----------------
// grid: x = q-tile (32, heavy-first), y = b*H + h.  256 threads = 4 waves x 16 q-rows.

__global__ __launch_bounds__(256, 2) void attn_kernel(
    const short* __restrict__ Qb, const short* __restrict__ Kb,
    const short* __restrict__ Vb, const short* __restrict__ Erb,
    short* __restrict__ Y)
{
  const int nq = LSEQ / 64;
  const int qt = (nq - 1) - blockIdx.x;      // dispatch heavy tiles first
  const int l0 = qt * 64;
  const int bh = blockIdx.y;
  const int bb = bh >> 4, hh = bh & 15;
  const int t = threadIdx.x;
  const int lane = t & 63, wave = t >> 6;
  const int g = lane >> 4, c = lane & 15;

  __shared__ short Ql[64 * 64];     // q tile, row-XOR swizzled
  __shared__ short Kl[64 * 64];     // k tile, swizzled
  __shared__ short Vt[64 * 64];     // V^T tile [d][m], swizzled
  __shared__ short Erl[128 * 64];   // Er band rows, swizzled
  __shared__ short Gl[4][16 * 128]; // per-wave rel-band product (bf16)
  __shared__ short Pl[4][16 * 64];  // per-wave P tile, swizzled

  const short* Qg = Qb + ((size_t)bh * LSEQ + l0) * HS;

  for (int i = 0; i < 2; ++i) {
    int ch = i * 256 + t;
    int row = ch >> 3, c8 = ch & 7;
    uint4 v = *reinterpret_cast<const uint4*>(Qg + row * HS + c8 * 8);
    int byte = row * 128 + ((c8 * 16) ^ ((row & 7) << 4));
    *reinterpret_cast<uint4*>(reinterpret_cast<char*>(Ql) + byte) = v;
  }
  __syncthreads();

  short8 qf[2];
#pragma unroll
  for (int kk = 0; kk < 2; ++kk) {
    int row = wave * 16 + c;
    int kbyte = (kk * 32 + g * 8) * 2;
    int byte = row * 128 + (kbyte ^ ((row & 7) << 4));
    qf[kk] = *reinterpret_cast<const short8*>(reinterpret_cast<char*>(Ql) + byte);
  }

  f32x4 acc_o[4] = {};
  float mrun[4], lrun[4];
#pragma unroll
  for (int r = 0; r < 4; ++r) { mrun[r] = -1e30f; lrun[r] = 0.0f; }

  const int nsteps = qt + 1;
  for (int step = 0; step < nsteps; ++step) {
    const int m0 = step * 64;
    const bool diag = (step == qt);
    __syncthreads();
    const short* Kg = Kb + ((size_t)bh * LSEQ + m0) * HS;
    const short* Vg = Vb + ((size_t)bh * LSEQ + m0) * HS;
    for (int i = 0; i < 2; ++i) {
      int ch = i * 256 + t;
      int row = ch >> 3, c8 = ch & 7;
      uint4 vk = *reinterpret_cast<const uint4*>(Kg + row * HS + c8 * 8);
      int byte = row * 128 + ((c8 * 16) ^ ((row & 7) << 4));
      *reinterpret_cast<uint4*>(reinterpret_cast<char*>(Kl) + byte) = vk;
      uint4 vv = *reinterpret_cast<const uint4*>(Vg + row * HS + c8 * 8);
      short tmp[8];
      *reinterpret_cast<uint4*>(tmp) = vv;
#pragma unroll
      for (int e = 0; e < 8; ++e) {
        int d = c8 * 8 + e;
        int byteT = d * 128 + ((row * 2) ^ ((d & 7) << 4));
        *reinterpret_cast<short*>(reinterpret_cast<char*>(Vt) + byteT) = tmp[e];
      }
    }
    int c0 = LSEQ - 1 - l0 + m0;
    for (int i = 0; i < 4; ++i) {
      int ch = i * 256 + t;
      int row = ch >> 3, c8 = ch & 7;
      int e = c0 - 63 + row;
      e = e < 0 ? 0 : (e > LSEQ - 1 ? LSEQ - 1 : e);
      uint4 ve = *reinterpret_cast<const uint4*>(Erb + (size_t)e * HS + c8 * 8);
      int byte = row * 128 + ((c8 * 16) ^ ((row & 7) << 4));
      *reinterpret_cast<uint4*>(reinterpret_cast<char*>(Erl) + byte) = ve;
    }
    __syncthreads();

    // G = Q @ ErBand^T : per-wave needed window is 5 subtiles starting at (3-wave)
    short* Gw = Gl[wave];
#pragma unroll
    for (int s5 = 0; s5 < 5; ++s5) {
      int ns = (3 - wave) + s5;
      f32x4 ga = {0.0f, 0.0f, 0.0f, 0.0f};
#pragma unroll
      for (int kk = 0; kk < 2; ++kk) {
        int row = ns * 16 + c;
        int kbyte = (kk * 32 + g * 8) * 2;
        int byte = row * 128 + (kbyte ^ ((row & 7) << 4));
        short8 ef = *reinterpret_cast<const short8*>(reinterpret_cast<char*>(Erl) + byte);
        ga = __builtin_amdgcn_mfma_f32_16x16x32_bf16(qf[kk], ef, ga, 0, 0, 0);
      }
#pragma unroll
      for (int r = 0; r < 4; ++r)
        Gw[(g * 4 + r) * 128 + ns * 16 + c] = f2bf(ga[r]);
    }

    // S = Q K^T
    f32x4 sa[4];
#pragma unroll
    for (int ns = 0; ns < 4; ++ns) {
      sa[ns] = (f32x4){0.0f, 0.0f, 0.0f, 0.0f};
#pragma unroll
      for (int kk = 0; kk < 2; ++kk) {
        int row = ns * 16 + c;
        int kbyte = (kk * 32 + g * 8) * 2;
        int byte = row * 128 + (kbyte ^ ((row & 7) << 4));
        short8 kf = *reinterpret_cast<const short8*>(reinterpret_cast<char*>(Kl) + byte);
        sa[ns] = __builtin_amdgcn_mfma_f32_16x16x32_bf16(qf[kk], kf, sa[ns], 0, 0, 0);
      }
    }

    // combine with skewed rel term, scale, mask
    float sv[4][4];
#pragma unroll
    for (int ns = 0; ns < 4; ++ns)
#pragma unroll
      for (int r = 0; r < 4; ++r) {
        int iw = g * 4 + r;
        int jg = 63 + ns * 16 + c - wave * 16 - iw;
        float srel = bf2f(Gw[iw * 128 + jg]);
        float x = (sa[ns][r] + srel) * 0.125f;
        if (diag && (ns * 16 + c > wave * 16 + iw)) x = -1e30f;
        sv[ns][r] = x;
      }

    // online softmax (row lives in a 16-lane group)
    float mnew[4], al[4];
#pragma unroll
    for (int r = 0; r < 4; ++r) {
      float mx = fmaxf(fmaxf(sv[0][r], sv[1][r]), fmaxf(sv[2][r], sv[3][r]));
      mx = fmaxf(mx, __shfl_xor(mx, 1));
      mx = fmaxf(mx, __shfl_xor(mx, 2));
      mx = fmaxf(mx, __shfl_xor(mx, 4));
      mx = fmaxf(mx, __shfl_xor(mx, 8));
      mnew[r] = fmaxf(mrun[r], mx);
      al[r] = __expf(mrun[r] - mnew[r]);
      mrun[r] = mnew[r];
    }
#pragma unroll
    for (int ns = 0; ns < 4; ++ns)
#pragma unroll
      for (int r = 0; r < 4; ++r)
        sv[ns][r] = __expf(sv[ns][r] - mnew[r]);
#pragma unroll
    for (int r = 0; r < 4; ++r) {
      float s = sv[0][r] + sv[1][r] + sv[2][r] + sv[3][r];
      s += __shfl_xor(s, 1);
      s += __shfl_xor(s, 2);
      s += __shfl_xor(s, 4);
      s += __shfl_xor(s, 8);
      lrun[r] = lrun[r] * al[r] + s;
    }
#pragma unroll
    for (int ns = 0; ns < 4; ++ns)
#pragma unroll
      for (int r = 0; r < 4; ++r)
        acc_o[ns][r] *= al[r];

    // P -> LDS (bf16, swizzled)
    short* Pw = Pl[wave];
#pragma unroll
    for (int ns = 0; ns < 4; ++ns)
#pragma unroll
      for (int r = 0; r < 4; ++r) {
        int row = g * 4 + r;
        int cbyte = (ns * 16 + c) * 2;
        int byte = row * 128 + (cbyte ^ ((row & 7) << 4));
        *reinterpret_cast<short*>(reinterpret_cast<char*>(Pw) + byte) = f2bf(sv[ns][r]);
      }

    // O += P V
#pragma unroll
    for (int kk = 0; kk < 2; ++kk) {
      int kbyte = (kk * 32 + g * 8) * 2;
      int byteP = c * 128 + (kbyte ^ ((c & 7) << 4));
      short8 pf = *reinterpret_cast<const short8*>(reinterpret_cast<char*>(Pw) + byteP);
#pragma unroll
      for (int ns = 0; ns < 4; ++ns) {
        int rowV = ns * 16 + c;
        int byteV = rowV * 128 + (kbyte ^ ((rowV & 7) << 4));
        short8 vf = *reinterpret_cast<const short8*>(reinterpret_cast<char*>(Vt) + byteV);
        acc_o[ns] = __builtin_amdgcn_mfma_f32_16x16x32_bf16(pf, vf, acc_o[ns], 0, 0, 0);
      }
    }
  }

#pragma unroll
  for (int ns = 0; ns < 4; ++ns)
#pragma unroll
    for (int r = 0; r < 4; ++r) {
      int row = g * 4 + r;
      float inv = 1.0f / lrun[r];
      int lg = l0 + wave * 16 + row;
      int d = ns * 16 + c;
      Y[((size_t)bb * LSEQ + lg) * DIM + hh * HS + d] = f2bf(acc_o[ns][r] * inv);
    }
}

// ---------------- launch ----------------

extern "C" void kernel_launch(void* const* d_in, const int* in_sizes, int n_in,
                              void* d_out, int out_size, void* d_ws, size_t ws_size,
                              hipStream_t stream)
{
  const float* x     = (const float*)d_in[0];
  const float* Wqkv  = (const float*)d_in[1];
  const float* bqkv  = (const float*)d_in[2];
  const float* Wproj = (const float*)d_in[3];
  const float* bproj = (const float*)d_in[4];
  const float* Er    = (const float*)d_in[5];

  char* ws = (char*)d_ws;
  short* xb     = (short*)(ws + 0);                       // 4096x1024 bf16
  short* WqkvT  = (short*)(ws + 8388608);                 // 3072x1024 bf16
  short* WprojT = (short*)(ws + 14680064);                // 1024x1024 bf16
  short* Erb    = (short*)(ws + 16777216);                // 2048x64 bf16
  short* qB     = (short*)(ws + 17039360);                // [2][16][2048][64] bf16
  short* kB     = (short*)(ws + 25427968);
  short* vB     = (short*)(ws + 33816576);
  short* yB     = (short*)(ws + 42205184);                // 4096x1024 bf16

  cast_kernel<<<4096, 256, 0, stream>>>(x, xb, 4096 * 1024 / 4);
  cast_kernel<<<128, 256, 0, stream>>>(Er, Erb, 2048 * 64 / 4);
  transpose_cast_kernel<<<dim3(3072 / 64, 1024 / 64), 256, 0, stream>>>(Wqkv, WqkvT, 1024, 3072);
  transpose_cast_kernel<<<dim3(1024 / 64, 1024 / 64), 256, 0, stream>>>(Wproj, WprojT, 1024, 1024);

  gemm_bt_kernel<0><<<dim3(3072 / 128, 4096 / 128), 256, 0, stream>>>(
      xb, WqkvT, bqkv, 4096, 3072, 1024, qB, kB, vB, nullptr);

  attn_kernel<<<dim3(32, 32), 256, 0, stream>>>(qB, kB, vB, Erb, yB);

  gemm_bt_kernel<1><<<dim3(1024 / 128, 4096 / 128), 256, 0, stream>>>(
      yB, WprojT, bproj, 4096, 1024, 1024, nullptr, nullptr, nullptr, (float*)d_out);
}

// Round 2
// 172.660 us; speedup vs baseline: 1.9431x; 1.9431x over previous
//
#include <hip/hip_runtime.h>
#include <hip/hip_bf16.h>

#define LSEQ 2048
#define NH 16
#define HS 64
#define DIM 1024

typedef __attribute__((ext_vector_type(8))) short short8;
typedef __attribute__((ext_vector_type(4))) float f32x4;

typedef const __attribute__((address_space(1))) void g_void_t;
typedef __attribute__((address_space(3))) void s_void_t;

static __device__ __forceinline__ short f2bf(float f) {
  __hip_bfloat16 h = __float2bfloat16(f);
  return __builtin_bit_cast(short, h);
}

// ---------------- prep kernels ----------------

__global__ void cast_kernel(const float* __restrict__ in, short* __restrict__ out, int n4) {
  int i = blockIdx.x * blockDim.x + threadIdx.x;
  if (i < n4) {
    float4 v = reinterpret_cast<const float4*>(in)[i];
    short4 o;
    o.x = f2bf(v.x); o.y = f2bf(v.y); o.z = f2bf(v.z); o.w = f2bf(v.w);
    reinterpret_cast<short4*>(out)[i] = o;
  }
}

// W: [K][N] f32  ->  Wt: [N][K] bf16
__global__ void transpose_cast_kernel(const float* __restrict__ W, short* __restrict__ Wt,
                                      int K, int N) {
  __shared__ float tile[64][65];
  int k0 = blockIdx.y * 64, n0 = blockIdx.x * 64;
  int t = threadIdx.x;
  int r4 = t >> 6, cc = t & 63;
  for (int i = 0; i < 16; ++i) {
    int row = i * 4 + r4;
    tile[row][cc] = W[(size_t)(k0 + row) * N + (n0 + cc)];
  }
  __syncthreads();
  for (int i = 0; i < 16; ++i) {
    int row = i * 4 + r4;
    Wt[(size_t)(n0 + row) * K + (k0 + cc)] = f2bf(tile[cc][row]);
  }
}

// V [bh][2048][64] bf16 -> Vt [bh][64][2048] bf16
__global__ void transpose_v_kernel(const short* __restrict__ V, short* __restrict__ Vt) {
  __shared__ short tile[64][65];
  int bh = blockIdx.y;
  int l0 = blockIdx.x * 64;
  int t = threadIdx.x;
  const short* src = V + ((size_t)bh * LSEQ + l0) * HS;
  for (int i = 0; i < 2; ++i) {
    int ch = i * 256 + t;
    int row = ch >> 3, c8 = ch & 7;
    uint4 v = *reinterpret_cast<const uint4*>(src + row * HS + c8 * 8);
    short tmp[8];
    *reinterpret_cast<uint4*>(tmp) = v;
#pragma unroll
    for (int e = 0; e < 8; ++e) tile[row][c8 * 8 + e] = tmp[e];
  }
  __syncthreads();
  short* dst = Vt + (size_t)bh * HS * LSEQ + l0;
  for (int i = 0; i < 2; ++i) {
    int ch = i * 256 + t;
    int d = ch >> 3, c8 = ch & 7;
    short tmp[8];
#pragma unroll
    for (int e = 0; e < 8; ++e) tmp[e] = tile[c8 * 8 + e][d];
    *reinterpret_cast<uint4*>(dst + (size_t)d * LSEQ + c8 * 8) = *reinterpret_cast<uint4*>(tmp);
  }
}

// ---------------- GEMM (A[M][K] bf16 row-major, Bt[N][K] bf16 row-major) ----------------

template<int MODE>
__global__ __launch_bounds__(256, 2) void gemm_bt_kernel(
    const short* __restrict__ A, const short* __restrict__ Bt,
    const float* __restrict__ bias, int M, int N, int K,
    short* __restrict__ oq, short* __restrict__ ok, short* __restrict__ ov,
    float* __restrict__ of)
{
  __shared__ short Al[128 * 32];
  __shared__ short Bl[128 * 32];
  const int m0 = blockIdx.y * 128, n0 = blockIdx.x * 128;
  const int t = threadIdx.x;
  const int lane = t & 63, wave = t >> 6;
  const int wr = wave >> 1, wc = wave & 1;
  const int g = lane >> 4, c = lane & 15;
  f32x4 acc[4][4] = {};

  for (int k0 = 0; k0 < K; k0 += 32) {
    __syncthreads();
    for (int i = 0; i < 2; ++i) {
      int ch = i * 256 + t;
      int row = ch >> 2, c8 = ch & 3;
      __builtin_amdgcn_global_load_lds(
          (g_void_t*)(A + (size_t)(m0 + row) * K + k0 + c8 * 8),
          (s_void_t*)(Al + (i * 256 + wave * 64) * 8), 16, 0, 0);
      __builtin_amdgcn_global_load_lds(
          (g_void_t*)(Bt + (size_t)(n0 + row) * K + k0 + c8 * 8),
          (s_void_t*)(Bl + (i * 256 + wave * 64) * 8), 16, 0, 0);
    }
    __syncthreads();
    short8 af[4], bf[4];
#pragma unroll
    for (int mi = 0; mi < 4; ++mi) {
      int row = wr * 64 + mi * 16 + c;
      af[mi] = *reinterpret_cast<const short8*>(Al + row * 32 + g * 8);
    }
#pragma unroll
    for (int ni = 0; ni < 4; ++ni) {
      int row = wc * 64 + ni * 16 + c;
      bf[ni] = *reinterpret_cast<const short8*>(Bl + row * 32 + g * 8);
    }
#pragma unroll
    for (int mi = 0; mi < 4; ++mi)
#pragma unroll
      for (int ni = 0; ni < 4; ++ni)
        acc[mi][ni] = __builtin_amdgcn_mfma_f32_16x16x32_bf16(af[mi], bf[ni], acc[mi][ni], 0, 0, 0);
  }

#pragma unroll
  for (int mi = 0; mi < 4; ++mi)
#pragma unroll
    for (int ni = 0; ni < 4; ++ni) {
      int n = n0 + wc * 64 + ni * 16 + c;
      float bv = bias[n];
#pragma unroll
      for (int r = 0; r < 4; ++r) {
        int m = m0 + wr * 64 + mi * 16 + g * 4 + r;
        float val = acc[mi][ni][r] + bv;
        if (MODE == 0) {
          int which = n >> 10;
          int hh2 = (n >> 6) & 15;
          int d = n & 63;
          int b = m >> 11, ll = m & 2047;
          short* dst = which == 0 ? oq : (which == 1 ? ok : ov);
          dst[(((size_t)b * NH + hh2) * LSEQ + ll) * HS + d] = f2bf(val);
        } else {
          of[(size_t)m * N + n] = val;
        }
      }
    }
}

// ---------------- fused flash attention with relative-position band ----------------
// 1D grid, heavy q-tiles first. 256 threads = 4 waves x 16 q-rows.
// K/V^T/Er double-buffered via global_load_lds (pre-swizzled source, linear dest),
// counted vmcnt(8), raw barriers. Skew term resolved with register shuffles.

__global__ __launch_bounds__(256, 2) void attn_kernel(
    const short* __restrict__ Qb, const short* __restrict__ Kb,
    const short* __restrict__ VTb, const short* __restrict__ Erb,
    short* __restrict__ Y)
{
  const int bid = blockIdx.x;
  const int qt = 31 - (bid >> 5);          // heavy tiles dispatched first
  const int bh = bid & 31;
  const int l0 = qt * 64;
  const int bb = bh >> 4, hh = bh & 15;
  const int t = threadIdx.x;
  const int lane = t & 63, wave = t >> 6;
  const int g = lane >> 4, c = lane & 15;
  const int r8 = lane >> 3;                // sub-row within a 1KB gl_lds chunk
  const int c16b = (lane & 7) * 16;        // 16B chunk byte within a 128B row

  __shared__ short Ql[64 * 64];            // 8 KB, row-XOR swizzled
  __shared__ short Kl[2][64 * 64];         // 16 KB
  __shared__ short Vl[2][64 * 64];         // 16 KB (V^T rows = d)
  __shared__ short El[2][128 * 64];        // 32 KB (Er band)
  __shared__ short Pl[4][16 * 64];         // 8 KB per-wave P

  // ---- stage Q (once) ----
  const short* Qg = Qb + ((size_t)bh * LSEQ + l0) * HS;
  for (int i = 0; i < 2; ++i) {
    int ch = i * 256 + t;
    int row = ch >> 3, c8 = ch & 7;
    uint4 v = *reinterpret_cast<const uint4*>(Qg + row * HS + c8 * 8);
    int byte = row * 128 + ((c8 * 16) ^ ((row & 7) << 4));
    *reinterpret_cast<uint4*>(reinterpret_cast<char*>(Ql) + byte) = v;
  }
  __syncthreads();

  short8 qf[2];
#pragma unroll
  for (int kk = 0; kk < 2; ++kk) {
    int row = wave * 16 + c;
    int byte = row * 128 + ((kk * 32 + g * 8) * 2 ^ ((row & 7) << 4));
    qf[kk] = *reinterpret_cast<const short8*>(reinterpret_cast<char*>(Ql) + byte);
  }

  f32x4 acc_o[4] = {};
  float mrun[4], lrun[4];
#pragma unroll
  for (int r = 0; r < 4; ++r) { mrun[r] = -1e30f; lrun[r] = 0.0f; }

  const int nsteps = qt + 1;

  auto issue_stage = [&](int step, int sel) {
    const int m0 = step * 64;
    const char* Kg = (const char*)(Kb + ((size_t)bh * LSEQ + m0) * HS);
#pragma unroll
    for (int j = 0; j < 2; ++j) {
      int row = wave * 16 + j * 8 + r8;
      __builtin_amdgcn_global_load_lds(
          (g_void_t*)(Kg + row * 128 + (c16b ^ ((row & 7) << 4))),
          (s_void_t*)(&Kl[sel][(wave * 16 + j * 8) * 64]), 16, 0, 0);
    }
#pragma unroll
    for (int j = 0; j < 2; ++j) {
      int row = wave * 16 + j * 8 + r8;  // d index
      const char* Vg = (const char*)(VTb + ((size_t)bh * HS + row) * LSEQ + m0);
      __builtin_amdgcn_global_load_lds(
          (g_void_t*)(Vg + (c16b ^ ((row & 7) << 4))),
          (s_void_t*)(&Vl[sel][(wave * 16 + j * 8) * 64]), 16, 0, 0);
    }
    const int c0 = LSEQ - 1 - l0 + m0;
#pragma unroll
    for (int j = 0; j < 4; ++j) {
      int row = wave * 32 + j * 8 + r8;
      int e = c0 - 63 + row;
      e = e < 0 ? 0 : (e > LSEQ - 1 ? LSEQ - 1 : e);
      __builtin_amdgcn_global_load_lds(
          (g_void_t*)((const char*)(Erb + (size_t)e * HS) + (c16b ^ ((row & 7) << 4))),
          (s_void_t*)(&El[sel][(wave * 32 + j * 8) * 64]), 16, 0, 0);
    }
  };

  issue_stage(0, 0);

  for (int step = 0; step < nsteps; ++step) {
    const int sel = step & 1;
    const bool diag = (step == qt);

    if (step + 1 < nsteps) {
      issue_stage(step + 1, sel ^ 1);
      asm volatile("s_waitcnt vmcnt(8)" ::: "memory");
    } else {
      asm volatile("s_waitcnt vmcnt(0)" ::: "memory");
    }
    __builtin_amdgcn_s_barrier();
    __builtin_amdgcn_sched_barrier(0);

    // ---- G = Q · ErBand^T (5 subtiles kept in registers) ----
    f32x4 ga[5];
#pragma unroll
    for (int s5 = 0; s5 < 5; ++s5) {
      int nsb = (3 - wave) + s5;
      ga[s5] = (f32x4){0.0f, 0.0f, 0.0f, 0.0f};
#pragma unroll
      for (int kk = 0; kk < 2; ++kk) {
        int row = nsb * 16 + c;
        int byte = row * 128 + ((kk * 32 + g * 8) * 2 ^ ((row & 7) << 4));
        short8 ef = *reinterpret_cast<const short8*>((char*)El[sel] + byte);
        ga[s5] = __builtin_amdgcn_mfma_f32_16x16x32_bf16(qf[kk], ef, ga[s5], 0, 0, 0);
      }
    }

    // ---- S = Q K^T ----
    f32x4 sa[4];
#pragma unroll
    for (int ns = 0; ns < 4; ++ns) {
      sa[ns] = (f32x4){0.0f, 0.0f, 0.0f, 0.0f};
#pragma unroll
      for (int kk = 0; kk < 2; ++kk) {
        int row = ns * 16 + c;
        int byte = row * 128 + ((kk * 32 + g * 8) * 2 ^ ((row & 7) << 4));
        short8 kf = *reinterpret_cast<const short8*>((char*)Kl[sel] + byte);
        sa[ns] = __builtin_amdgcn_mfma_f32_16x16x32_bf16(qf[kk], kf, sa[ns], 0, 0, 0);
      }
    }

    // ---- skew: Srel[i][j] = G[i][63 + j - i] via intra-group shuffles ----
    float sv[4][4];
#pragma unroll
    for (int r = 0; r < 4; ++r) {
      int i4 = g * 4 + r;
      int u = c + 15 - i4;                 // 0..30
      int srcl = (g << 4) | (u & 15);
      bool lo = (u < 16);
#pragma unroll
      for (int ns = 0; ns < 4; ++ns) {
        float va = __shfl(ga[ns][r], srcl, 64);
        float vb = __shfl(ga[ns + 1][r], srcl, 64);
        float srel = lo ? va : vb;
        float x = (sa[ns][r] + srel) * 0.125f;
        if (diag && (ns * 16 + c > wave * 16 + i4)) x = -1e30f;
        sv[ns][r] = x;
      }
    }

    // ---- online softmax (row lives in a 16-lane group) ----
    float mnew[4], al[4];
#pragma unroll
    for (int r = 0; r < 4; ++r) {
      float mx = fmaxf(fmaxf(sv[0][r], sv[1][r]), fmaxf(sv[2][r], sv[3][r]));
      mx = fmaxf(mx, __shfl_xor(mx, 1));
      mx = fmaxf(mx, __shfl_xor(mx, 2));
      mx = fmaxf(mx, __shfl_xor(mx, 4));
      mx = fmaxf(mx, __shfl_xor(mx, 8));
      mnew[r] = fmaxf(mrun[r], mx);
      al[r] = __expf(mrun[r] - mnew[r]);
      mrun[r] = mnew[r];
    }
#pragma unroll
    for (int ns = 0; ns < 4; ++ns)
#pragma unroll
      for (int r = 0; r < 4; ++r)
        sv[ns][r] = __expf(sv[ns][r] - mnew[r]);
#pragma unroll
    for (int r = 0; r < 4; ++r) {
      float s = sv[0][r] + sv[1][r] + sv[2][r] + sv[3][r];
      s += __shfl_xor(s, 1);
      s += __shfl_xor(s, 2);
      s += __shfl_xor(s, 4);
      s += __shfl_xor(s, 8);
      lrun[r] = lrun[r] * al[r] + s;
    }
#pragma unroll
    for (int ns = 0; ns < 4; ++ns)
#pragma unroll
      for (int r = 0; r < 4; ++r)
        acc_o[ns][r] *= al[r];

    // ---- P -> LDS (bf16, swizzled, per-wave) ----
    short* Pw = Pl[wave];
#pragma unroll
    for (int ns = 0; ns < 4; ++ns)
#pragma unroll
      for (int r = 0; r < 4; ++r) {
        int row = g * 4 + r;
        int byte = row * 128 + (((ns * 16 + c) * 2) ^ ((row & 7) << 4));
        *reinterpret_cast<short*>(reinterpret_cast<char*>(Pw) + byte) = f2bf(sv[ns][r]);
      }

    // ---- O += P V ----
#pragma unroll
    for (int kk = 0; kk < 2; ++kk) {
      int kbyte = (kk * 32 + g * 8) * 2;
      int byteP = c * 128 + (kbyte ^ ((c & 7) << 4));
      short8 pf = *reinterpret_cast<const short8*>(reinterpret_cast<char*>(Pw) + byteP);
#pragma unroll
      for (int ns = 0; ns < 4; ++ns) {
        int rowV = ns * 16 + c;
        int byteV = rowV * 128 + (kbyte ^ ((rowV & 7) << 4));
        short8 vf = *reinterpret_cast<const short8*>((char*)Vl[sel] + byteV);
        acc_o[ns] = __builtin_amdgcn_mfma_f32_16x16x32_bf16(pf, vf, acc_o[ns], 0, 0, 0);
      }
    }

    __builtin_amdgcn_sched_barrier(0);
    __builtin_amdgcn_s_barrier();
  }

#pragma unroll
  for (int ns = 0; ns < 4; ++ns)
#pragma unroll
    for (int r = 0; r < 4; ++r) {
      int row = g * 4 + r;
      float inv = 1.0f / lrun[r];
      int lg = l0 + wave * 16 + row;
      int d = ns * 16 + c;
      Y[((size_t)bb * LSEQ + lg) * DIM + hh * HS + d] = f2bf(acc_o[ns][r] * inv);
    }
}

// ---------------- launch ----------------

extern "C" void kernel_launch(void* const* d_in, const int* in_sizes, int n_in,
                              void* d_out, int out_size, void* d_ws, size_t ws_size,
                              hipStream_t stream)
{
  const float* x     = (const float*)d_in[0];
  const float* Wqkv  = (const float*)d_in[1];
  const float* bqkv  = (const float*)d_in[2];
  const float* Wproj = (const float*)d_in[3];
  const float* bproj = (const float*)d_in[4];
  const float* Er    = (const float*)d_in[5];

  char* ws = (char*)d_ws;
  short* xb     = (short*)(ws + 0);                       // 4096x1024 bf16 (GEMM1 input)
  short* WqkvT  = (short*)(ws + 8388608);                 // 3072x1024 bf16
  short* WprojT = (short*)(ws + 14680064);                // 1024x1024 bf16
  short* Erb    = (short*)(ws + 16777216);                // 2048x64 bf16
  short* qB     = (short*)(ws + 17039360);                // [32][2048][64] bf16
  short* kB     = (short*)(ws + 25427968);
  short* vB     = (short*)(ws + 33816576);
  short* yB     = (short*)(ws + 42205184);                // 4096x1024 bf16
  short* vT     = xb;                                     // reuse xb after GEMM1: [32][64][2048]

  cast_kernel<<<4096, 256, 0, stream>>>(x, xb, 4096 * 1024 / 4);
  cast_kernel<<<128, 256, 0, stream>>>(Er, Erb, 2048 * 64 / 4);
  transpose_cast_kernel<<<dim3(3072 / 64, 1024 / 64), 256, 0, stream>>>(Wqkv, WqkvT, 1024, 3072);
  transpose_cast_kernel<<<dim3(1024 / 64, 1024 / 64), 256, 0, stream>>>(Wproj, WprojT, 1024, 1024);

  gemm_bt_kernel<0><<<dim3(3072 / 128, 4096 / 128), 256, 0, stream>>>(
      xb, WqkvT, bqkv, 4096, 3072, 1024, qB, kB, vB, nullptr);

  transpose_v_kernel<<<dim3(32, 32), 256, 0, stream>>>(vB, vT);

  attn_kernel<<<dim3(1024), 256, 0, stream>>>(qB, kB, vT, Erb, yB);

  gemm_bt_kernel<1><<<dim3(1024 / 128, 4096 / 128), 256, 0, stream>>>(
      yB, WprojT, bproj, 4096, 1024, 1024, nullptr, nullptr, nullptr, (float*)d_out);
}

// Round 3
// 153.194 us; speedup vs baseline: 2.1900x; 1.1271x over previous
//
#include <hip/hip_runtime.h>
#include <hip/hip_bf16.h>

#define LSEQ 2048
#define NH 16
#define HS 64
#define DIM 1024

typedef __attribute__((ext_vector_type(8))) short short8;
typedef __attribute__((ext_vector_type(4))) float f32x4;

typedef const __attribute__((address_space(1))) void g_void_t;
typedef __attribute__((address_space(3))) void s_void_t;

// 0.125 (1/sqrt(hs)) * log2(e): folded into Q so softmax runs in base 2.
#define QSCALE 0.18033688011112042f

static __device__ __forceinline__ short f2bf(float f) {
  __hip_bfloat16 h = __float2bfloat16(f);
  return __builtin_bit_cast(short, h);
}

static __device__ __forceinline__ float fexp2(float x) {
#if __has_builtin(__builtin_amdgcn_exp2f)
  return __builtin_amdgcn_exp2f(x);
#else
  float r; asm("v_exp_f32 %0, %1" : "=v"(r) : "v"(x)); return r;
#endif
}

// DPP cross-lane move (VALU-only, no LDS pipe).
template<int CTRL>
static __device__ __forceinline__ float dpp_mov(float x) {
  return __builtin_bit_cast(float,
      __builtin_amdgcn_update_dpp(0, __builtin_bit_cast(int, x), CTRL, 0xF, 0xF, true));
}
// Butterfly over 16-lane group with independent xor masks {1,2,7,15}:
// quad_perm[1,0,3,2]=0xB1, quad_perm[2,3,0,1]=0x4E, row_half_mirror=0x141, row_mirror=0x140.
static __device__ __forceinline__ float redmax16(float x) {
  x = fmaxf(x, dpp_mov<0xB1>(x));
  x = fmaxf(x, dpp_mov<0x4E>(x));
  x = fmaxf(x, dpp_mov<0x141>(x));
  x = fmaxf(x, dpp_mov<0x140>(x));
  return x;
}
static __device__ __forceinline__ float redsum16(float x) {
  x += dpp_mov<0xB1>(x);
  x += dpp_mov<0x4E>(x);
  x += dpp_mov<0x141>(x);
  x += dpp_mov<0x140>(x);
  return x;
}

// ---------------- prep kernels ----------------

__global__ void cast_kernel(const float* __restrict__ in, short* __restrict__ out, int n4) {
  int i = blockIdx.x * blockDim.x + threadIdx.x;
  if (i < n4) {
    float4 v = reinterpret_cast<const float4*>(in)[i];
    short4 o;
    o.x = f2bf(v.x); o.y = f2bf(v.y); o.z = f2bf(v.z); o.w = f2bf(v.w);
    reinterpret_cast<short4*>(out)[i] = o;
  }
}

// W: [K][N] f32  ->  Wt: [N][K] bf16
__global__ void transpose_cast_kernel(const float* __restrict__ W, short* __restrict__ Wt,
                                      int K, int N) {
  __shared__ float tile[64][65];
  int k0 = blockIdx.y * 64, n0 = blockIdx.x * 64;
  int t = threadIdx.x;
  int r4 = t >> 6, cc = t & 63;
  for (int i = 0; i < 16; ++i) {
    int row = i * 4 + r4;
    tile[row][cc] = W[(size_t)(k0 + row) * N + (n0 + cc)];
  }
  __syncthreads();
  for (int i = 0; i < 16; ++i) {
    int row = i * 4 + r4;
    Wt[(size_t)(n0 + row) * K + (k0 + cc)] = f2bf(tile[cc][row]);
  }
}

// V [bh][2048][64] bf16 -> Vt [bh][64][2048] bf16
__global__ void transpose_v_kernel(const short* __restrict__ V, short* __restrict__ Vt) {
  __shared__ short tile[64][65];
  int bh = blockIdx.y;
  int l0 = blockIdx.x * 64;
  int t = threadIdx.x;
  const short* src = V + ((size_t)bh * LSEQ + l0) * HS;
  for (int i = 0; i < 2; ++i) {
    int ch = i * 256 + t;
    int row = ch >> 3, c8 = ch & 7;
    uint4 v = *reinterpret_cast<const uint4*>(src + row * HS + c8 * 8);
    short tmp[8];
    *reinterpret_cast<uint4*>(tmp) = v;
#pragma unroll
    for (int e = 0; e < 8; ++e) tile[row][c8 * 8 + e] = tmp[e];
  }
  __syncthreads();
  short* dst = Vt + (size_t)bh * HS * LSEQ + l0;
  for (int i = 0; i < 2; ++i) {
    int ch = i * 256 + t;
    int d = ch >> 3, c8 = ch & 7;
    short tmp[8];
#pragma unroll
    for (int e = 0; e < 8; ++e) tmp[e] = tile[c8 * 8 + e][d];
    *reinterpret_cast<uint4*>(dst + (size_t)d * LSEQ + c8 * 8) = *reinterpret_cast<uint4*>(tmp);
  }
}

// ---------------- GEMM (A[M][K] bf16 row-major, Bt[N][K] bf16 row-major) ----------------
// MODE 0: scatter qkv (q pre-scaled by QSCALE). MODE 1: f32 out + bias.

template<int MODE>
__global__ __launch_bounds__(256, 2) void gemm_bt_kernel(
    const short* __restrict__ A, const short* __restrict__ Bt,
    const float* __restrict__ bias, int M, int N, int K,
    short* __restrict__ oq, short* __restrict__ ok, short* __restrict__ ov,
    float* __restrict__ of)
{
  __shared__ short Al[128 * 32];
  __shared__ short Bl[128 * 32];
  const int m0 = blockIdx.y * 128, n0 = blockIdx.x * 128;
  const int t = threadIdx.x;
  const int lane = t & 63, wave = t >> 6;
  const int wr = wave >> 1, wc = wave & 1;
  const int g = lane >> 4, c = lane & 15;
  f32x4 acc[4][4] = {};

  for (int k0 = 0; k0 < K; k0 += 32) {
    __syncthreads();
    for (int i = 0; i < 2; ++i) {
      int ch = i * 256 + t;
      int row = ch >> 2, c8 = ch & 3;
      __builtin_amdgcn_global_load_lds(
          (g_void_t*)(A + (size_t)(m0 + row) * K + k0 + c8 * 8),
          (s_void_t*)(Al + (i * 256 + wave * 64) * 8), 16, 0, 0);
      __builtin_amdgcn_global_load_lds(
          (g_void_t*)(Bt + (size_t)(n0 + row) * K + k0 + c8 * 8),
          (s_void_t*)(Bl + (i * 256 + wave * 64) * 8), 16, 0, 0);
    }
    __syncthreads();
    short8 af[4], bf[4];
#pragma unroll
    for (int mi = 0; mi < 4; ++mi) {
      int row = wr * 64 + mi * 16 + c;
      af[mi] = *reinterpret_cast<const short8*>(Al + row * 32 + g * 8);
    }
#pragma unroll
    for (int ni = 0; ni < 4; ++ni) {
      int row = wc * 64 + ni * 16 + c;
      bf[ni] = *reinterpret_cast<const short8*>(Bl + row * 32 + g * 8);
    }
#pragma unroll
    for (int mi = 0; mi < 4; ++mi)
#pragma unroll
      for (int ni = 0; ni < 4; ++ni)
        acc[mi][ni] = __builtin_amdgcn_mfma_f32_16x16x32_bf16(af[mi], bf[ni], acc[mi][ni], 0, 0, 0);
  }

#pragma unroll
  for (int mi = 0; mi < 4; ++mi)
#pragma unroll
    for (int ni = 0; ni < 4; ++ni) {
      int n = n0 + wc * 64 + ni * 16 + c;
      float bv = bias[n];
#pragma unroll
      for (int r = 0; r < 4; ++r) {
        int m = m0 + wr * 64 + mi * 16 + g * 4 + r;
        float val = acc[mi][ni][r] + bv;
        if (MODE == 0) {
          int which = n >> 10;
          int hh2 = (n >> 6) & 15;
          int d = n & 63;
          int b = m >> 11, ll = m & 2047;
          if (which == 0) val *= QSCALE;
          short* dst = which == 0 ? oq : (which == 1 ? ok : ov);
          dst[(((size_t)b * NH + hh2) * LSEQ + ll) * HS + d] = f2bf(val);
        } else {
          of[(size_t)m * N + n] = val;
        }
      }
    }
}

// ---------------- fused flash attention with relative-position band ----------------
// grid 512: wg = (pair p, bh); processes q-tiles 31-p and p -> 33 steps each wg,
// exactly 2 wg/CU resident, no tail. DPP softmax reductions, base-2 exp,
// defer-rescale, double-buffered K/V^T/Er via global_load_lds + vmcnt(8).

__global__ __launch_bounds__(256, 2) void attn_kernel(
    const short* __restrict__ Qb, const short* __restrict__ Kb,
    const short* __restrict__ VTb, const short* __restrict__ Erb,
    short* __restrict__ Y)
{
  const int bid = blockIdx.x;
  const int pair = bid >> 5;
  const int bh = bid & 31;
  const int bb = bh >> 4, hh = bh & 15;
  const int t = threadIdx.x;
  const int lane = t & 63, wave = t >> 6;
  const int g = lane >> 4, c = lane & 15;
  const int r8 = lane >> 3;
  const int c16b = (lane & 7) * 16;

  __shared__ short Ql[64 * 64];            // 8 KB, row-XOR swizzled
  __shared__ short Kl[2][64 * 64];         // 16 KB
  __shared__ short Vl[2][64 * 64];         // 16 KB (V^T rows = d)
  __shared__ short El[2][128 * 64];        // 32 KB (Er band)
  __shared__ short Pl[4][16 * 64];         // 8 KB per-wave P

  auto process = [&](int qt) {
    const int l0 = qt * 64;

    // ---- stage Q ----
    const short* Qg = Qb + ((size_t)bh * LSEQ + l0) * HS;
    for (int i = 0; i < 2; ++i) {
      int ch = i * 256 + t;
      int row = ch >> 3, c8 = ch & 7;
      uint4 v = *reinterpret_cast<const uint4*>(Qg + row * HS + c8 * 8);
      int byte = row * 128 + ((c8 * 16) ^ ((row & 7) << 4));
      *reinterpret_cast<uint4*>(reinterpret_cast<char*>(Ql) + byte) = v;
    }
    __syncthreads();

    short8 qf[2];
#pragma unroll
    for (int kk = 0; kk < 2; ++kk) {
      int row = wave * 16 + c;
      int byte = row * 128 + ((kk * 32 + g * 8) * 2 ^ ((row & 7) << 4));
      qf[kk] = *reinterpret_cast<const short8*>(reinterpret_cast<char*>(Ql) + byte);
    }

    f32x4 acc_o[4] = {};
    float mrun[4], lrun[4];
#pragma unroll
    for (int r = 0; r < 4; ++r) { mrun[r] = -1e30f; lrun[r] = 0.0f; }

    const int nsteps = qt + 1;

    auto issue_stage = [&](int step, int sel) {
      const int m0 = step * 64;
      const char* Kg = (const char*)(Kb + ((size_t)bh * LSEQ + m0) * HS);
#pragma unroll
      for (int j = 0; j < 2; ++j) {
        int row = wave * 16 + j * 8 + r8;
        __builtin_amdgcn_global_load_lds(
            (g_void_t*)(Kg + row * 128 + (c16b ^ ((row & 7) << 4))),
            (s_void_t*)(&Kl[sel][(wave * 16 + j * 8) * 64]), 16, 0, 0);
      }
#pragma unroll
      for (int j = 0; j < 2; ++j) {
        int row = wave * 16 + j * 8 + r8;  // d index
        const char* Vg = (const char*)(VTb + ((size_t)bh * HS + row) * LSEQ + m0);
        __builtin_amdgcn_global_load_lds(
            (g_void_t*)(Vg + (c16b ^ ((row & 7) << 4))),
            (s_void_t*)(&Vl[sel][(wave * 16 + j * 8) * 64]), 16, 0, 0);
      }
      const int c0 = LSEQ - 1 - l0 + m0;
#pragma unroll
      for (int j = 0; j < 4; ++j) {
        int row = wave * 32 + j * 8 + r8;
        int e = c0 - 63 + row;
        e = e < 0 ? 0 : (e > LSEQ - 1 ? LSEQ - 1 : e);
        __builtin_amdgcn_global_load_lds(
            (g_void_t*)((const char*)(Erb + (size_t)e * HS) + (c16b ^ ((row & 7) << 4))),
            (s_void_t*)(&El[sel][(wave * 32 + j * 8) * 64]), 16, 0, 0);
      }
    };

    issue_stage(0, 0);

    for (int step = 0; step < nsteps; ++step) {
      const int sel = step & 1;
      const bool diag = (step == qt);

      if (step + 1 < nsteps) {
        issue_stage(step + 1, sel ^ 1);
        asm volatile("s_waitcnt vmcnt(8)" ::: "memory");
      } else {
        asm volatile("s_waitcnt vmcnt(0)" ::: "memory");
      }
      __builtin_amdgcn_s_barrier();
      __builtin_amdgcn_sched_barrier(0);

      // ---- G = Q · ErBand^T (5 window subtiles in registers) ----
      f32x4 ga[5];
#pragma unroll
      for (int s5 = 0; s5 < 5; ++s5) {
        int nsb = (3 - wave) + s5;
        ga[s5] = (f32x4){0.0f, 0.0f, 0.0f, 0.0f};
#pragma unroll
        for (int kk = 0; kk < 2; ++kk) {
          int row = nsb * 16 + c;
          int byte = row * 128 + ((kk * 32 + g * 8) * 2 ^ ((row & 7) << 4));
          short8 ef = *reinterpret_cast<const short8*>((char*)El[sel] + byte);
          ga[s5] = __builtin_amdgcn_mfma_f32_16x16x32_bf16(qf[kk], ef, ga[s5], 0, 0, 0);
        }
      }

      // ---- S = Q K^T ----
      f32x4 sa[4];
#pragma unroll
      for (int ns = 0; ns < 4; ++ns) {
        sa[ns] = (f32x4){0.0f, 0.0f, 0.0f, 0.0f};
#pragma unroll
        for (int kk = 0; kk < 2; ++kk) {
          int row = ns * 16 + c;
          int byte = row * 128 + ((kk * 32 + g * 8) * 2 ^ ((row & 7) << 4));
          short8 kf = *reinterpret_cast<const short8*>((char*)Kl[sel] + byte);
          sa[ns] = __builtin_amdgcn_mfma_f32_16x16x32_bf16(qf[kk], kf, sa[ns], 0, 0, 0);
        }
      }

      // ---- skew + mask (Q already carries 0.125*log2e) ----
      float sv[4][4];
#pragma unroll
      for (int r = 0; r < 4; ++r) {
        int i4 = g * 4 + r;
        int u0 = c + 15 - i4;                // 0..30
        int srcl = (g << 4) | (u0 & 15);
        float bp[5];
#pragma unroll
        for (int s5 = 0; s5 < 5; ++s5) bp[s5] = __shfl(ga[s5][r], srcl, 64);
        bool lo = (u0 < 16);
#pragma unroll
        for (int ns = 0; ns < 4; ++ns) {
          float srel = lo ? bp[ns] : bp[ns + 1];
          float x = sa[ns][r] + srel;
          if (diag && (ns * 16 + c > wave * 16 + i4)) x = -1e30f;
          sv[ns][r] = x;
        }
      }

      // ---- online softmax, DPP reductions, defer-rescale ----
      float mx[4];
      bool need = false;
#pragma unroll
      for (int r = 0; r < 4; ++r) {
        float m = fmaxf(fmaxf(sv[0][r], sv[1][r]), fmaxf(sv[2][r], sv[3][r]));
        mx[r] = redmax16(m);
        need = need || (mx[r] > mrun[r] + 4.0f);
      }
      if (__ballot(need)) {
#pragma unroll
        for (int r = 0; r < 4; ++r) {
          float mnew = fmaxf(mrun[r], mx[r]);
          float al = fexp2(mrun[r] - mnew);
          mrun[r] = mnew;
          lrun[r] *= al;
#pragma unroll
          for (int ns = 0; ns < 4; ++ns) acc_o[ns][r] *= al;
        }
      }
#pragma unroll
      for (int ns = 0; ns < 4; ++ns)
#pragma unroll
        for (int r = 0; r < 4; ++r)
          sv[ns][r] = fexp2(sv[ns][r] - mrun[r]);
#pragma unroll
      for (int r = 0; r < 4; ++r) {
        float s = (sv[0][r] + sv[1][r]) + (sv[2][r] + sv[3][r]);
        lrun[r] += redsum16(s);
      }

      // ---- P -> LDS (bf16, swizzled, per-wave) ----
      short* Pw = Pl[wave];
#pragma unroll
      for (int ns = 0; ns < 4; ++ns)
#pragma unroll
        for (int r = 0; r < 4; ++r) {
          int row = g * 4 + r;
          int byte = row * 128 + (((ns * 16 + c) * 2) ^ ((row & 7) << 4));
          *reinterpret_cast<short*>(reinterpret_cast<char*>(Pw) + byte) = f2bf(sv[ns][r]);
        }

      // ---- O += P V ----
#pragma unroll
      for (int kk = 0; kk < 2; ++kk) {
        int kbyte = (kk * 32 + g * 8) * 2;
        int byteP = c * 128 + (kbyte ^ ((c & 7) << 4));
        short8 pf = *reinterpret_cast<const short8*>(reinterpret_cast<char*>(Pw) + byteP);
#pragma unroll
        for (int ns = 0; ns < 4; ++ns) {
          int rowV = ns * 16 + c;
          int byteV = rowV * 128 + (kbyte ^ ((rowV & 7) << 4));
          short8 vf = *reinterpret_cast<const short8*>((char*)Vl[sel] + byteV);
          acc_o[ns] = __builtin_amdgcn_mfma_f32_16x16x32_bf16(pf, vf, acc_o[ns], 0, 0, 0);
        }
      }

      __builtin_amdgcn_sched_barrier(0);
      __builtin_amdgcn_s_barrier();
    }

    // ---- epilogue ----
#pragma unroll
    for (int ns = 0; ns < 4; ++ns)
#pragma unroll
      for (int r = 0; r < 4; ++r) {
        int row = g * 4 + r;
        float inv = 1.0f / lrun[r];
        int lg = l0 + wave * 16 + row;
        int d = ns * 16 + c;
        Y[((size_t)bb * LSEQ + lg) * DIM + hh * HS + d] = f2bf(acc_o[ns][r] * inv);
      }
  };

  process(31 - pair);
  process(pair);
}

// ---------------- launch ----------------

extern "C" void kernel_launch(void* const* d_in, const int* in_sizes, int n_in,
                              void* d_out, int out_size, void* d_ws, size_t ws_size,
                              hipStream_t stream)
{
  const float* x     = (const float*)d_in[0];
  const float* Wqkv  = (const float*)d_in[1];
  const float* bqkv  = (const float*)d_in[2];
  const float* Wproj = (const float*)d_in[3];
  const float* bproj = (const float*)d_in[4];
  const float* Er    = (const float*)d_in[5];

  char* ws = (char*)d_ws;
  short* xb     = (short*)(ws + 0);                       // 4096x1024 bf16 (GEMM1 input)
  short* WqkvT  = (short*)(ws + 8388608);                 // 3072x1024 bf16
  short* WprojT = (short*)(ws + 14680064);                // 1024x1024 bf16
  short* Erb    = (short*)(ws + 16777216);                // 2048x64 bf16
  short* qB     = (short*)(ws + 17039360);                // [32][2048][64] bf16
  short* kB     = (short*)(ws + 25427968);
  short* vB     = (short*)(ws + 33816576);
  short* yB     = (short*)(ws + 42205184);                // 4096x1024 bf16
  short* vT     = xb;                                     // reuse xb after GEMM1: [32][64][2048]

  cast_kernel<<<4096, 256, 0, stream>>>(x, xb, 4096 * 1024 / 4);
  cast_kernel<<<128, 256, 0, stream>>>(Er, Erb, 2048 * 64 / 4);
  transpose_cast_kernel<<<dim3(3072 / 64, 1024 / 64), 256, 0, stream>>>(Wqkv, WqkvT, 1024, 3072);
  transpose_cast_kernel<<<dim3(1024 / 64, 1024 / 64), 256, 0, stream>>>(Wproj, WprojT, 1024, 1024);

  gemm_bt_kernel<0><<<dim3(3072 / 128, 4096 / 128), 256, 0, stream>>>(
      xb, WqkvT, bqkv, 4096, 3072, 1024, qB, kB, vB, nullptr);

  transpose_v_kernel<<<dim3(32, 32), 256, 0, stream>>>(vB, vT);

  attn_kernel<<<dim3(512), 256, 0, stream>>>(qB, kB, vT, Erb, yB);

  gemm_bt_kernel<1><<<dim3(1024 / 128, 4096 / 128), 256, 0, stream>>>(
      yB, WprojT, bproj, 4096, 1024, 1024, nullptr, nullptr, nullptr, (float*)d_out);
}